// Round 12
// baseline (284.212 us; speedup 1.0000x reference)
//
#include <hip/hip_runtime.h>
#include <hip/hip_fp16.h>
#include <math.h>

#define N_NODES 100000
#define N_EDGES 1600000
#define F_IN 8
#define HID 32
#define HEADS 4
#define F1 128    // HEADS*HID
#define F2 16     // OUT
#define NB 391          // buckets of 256 nodes
#define NBLK_BIN 391    // edge-binning blocks of 4096 edges
#define NBLK_D1 3125    // dense1 blocks of 32 nodes
#define BCAP 4864       // per-bucket capacity (mean 4092, sd ~64 -> 12 sigma)

__device__ __forceinline__ float leaky(float x){ return x > 0.f ? x : 0.2f * x; }
__device__ __forceinline__ float elu1(float x){ return x > 0.f ? x : __expf(x) - 1.f; }

__device__ __forceinline__ __half2 shfl_xor_h2(__half2 v, int m){
    int iv = *(int*)&v;
    iv = __shfl_xor(iv, m);
    return *(__half2*)&iv;
}

// fp16 packed FMA of one 16B slice (8 halves) into 4 half2 accumulators
__device__ __forceinline__ void pkfma4(__half2* acc, __half2 w2, const uint4& r){
    const __half2* p = (const __half2*)&r;
    #pragma unroll
    for (int k = 0; k < 4; k++) acc[k] = __hfma2(w2, p[k], acc[k]);
}

// ---------------- Fused: edge binning (blocks 0..390) + layer-1 dense (rest, 32 nodes/block) ----------------
__global__ __launch_bounds__(256) void k_build_dense1(
    const int* __restrict__ src, const int* __restrict__ dst,
    int* __restrict__ bucketCnt, unsigned int* __restrict__ ebuf,
    const float* __restrict__ x, const float* __restrict__ W1,
    const float* __restrict__ as1w, const float* __restrict__ ad1w,
    __half* __restrict__ h1h, float* __restrict__ a_s1, float* __restrict__ a_d1){
    __shared__ float smem[1536];
    int t = threadIdx.x;
    if (blockIdx.x < NBLK_BIN){
        // ---- edge binning: 4096 edges -> 391 coarse buckets, line-local writes ----
        int* hist    = (int*)smem;
        int* basePos = hist + NB;
        int* cur     = basePos + NB;
        for (int j = t; j < NB; j += 256) hist[j] = 0;
        __syncthreads();
        int base = blockIdx.x * 4096;
        int dv[16];                        // register-cache dst (skip re-read in scatter pass)
        #pragma unroll
        for (int j = 0; j < 16; j++){
            int e = base + j * 256 + t;
            dv[j] = (e < N_EDGES) ? dst[e] : -1;
            if (dv[j] >= 0) atomicAdd(&hist[dv[j] >> 8], 1);
        }
        __syncthreads();
        for (int j = t; j < NB; j += 256){
            int h = hist[j];
            if (h) basePos[j] = atomicAdd(&bucketCnt[j], h);
            cur[j] = 0;
        }
        __syncthreads();
        #pragma unroll
        for (int j = 0; j < 16; j++){
            if (dv[j] >= 0){
                int e = base + j * 256 + t;
                int d = dv[j];
                int b = d >> 8;
                int off = atomicAdd(&cur[b], 1);
                ebuf[b * BCAP + basePos[b] + off] = ((unsigned)(d & 255) << 17) | (unsigned)src[e];
            }
        }
    } else {
        // ---- layer-1 dense: 32 nodes/block, W1 staged ONCE (cuts W1 re-fetch 4x) ----
        float* W1s  = smem;          // 1024
        float* atts = smem + 1024;   // 128
        float* attd = smem + 1152;   // 128
        float* xs   = smem + 1280;   // 256 (x for all 32 nodes)
        int bid = blockIdx.x - NBLK_BIN;
        ((float4*)W1s)[t] = ((const float4*)W1)[t];
        if (t < 128){ atts[t] = as1w[t]; attd[t] = ad1w[t]; }
        xs[t] = x[bid * 256 + t];
        __syncthreads();

        int ln = t >> 5, l32 = t & 31;
        int j0 = l32 * 4;
        int hd = l32 >> 3;
        int dl = j0 & 31;
        #pragma unroll
        for (int it = 0; it < 4; it++){
            int lnode = it * 8 + ln;
            int n = bid * 32 + lnode;
            float xr[8];
            #pragma unroll
            for (int k = 0; k < 8; k++) xr[k] = xs[lnode * 8 + k];
            float o0 = 0, o1 = 0, o2 = 0, o3 = 0;
            #pragma unroll
            for (int k = 0; k < 8; k++){
                float4 w4 = ((const float4*)(W1s + k * F1))[l32];
                o0 += xr[k] * w4.x; o1 += xr[k] * w4.y; o2 += xr[k] * w4.z; o3 += xr[k] * w4.w;
            }
            float ps = o0 * atts[hd * 32 + dl] + o1 * atts[hd * 32 + dl + 1]
                     + o2 * atts[hd * 32 + dl + 2] + o3 * atts[hd * 32 + dl + 3];
            float pd = o0 * attd[hd * 32 + dl] + o1 * attd[hd * 32 + dl + 1]
                     + o2 * attd[hd * 32 + dl + 2] + o3 * attd[hd * 32 + dl + 3];
            ps += __shfl_down(ps, 4, 8); ps += __shfl_down(ps, 2, 8); ps += __shfl_down(ps, 1, 8);
            pd += __shfl_down(pd, 4, 8); pd += __shfl_down(pd, 2, 8); pd += __shfl_down(pd, 1, 8);
            if ((l32 & 7) == 0){ a_s1[n * 4 + hd] = ps; a_d1[n * 4 + hd] = pd; }
            __half2* hp = (__half2*)(h1h + (size_t)n * F1 + j0);
            hp[0] = __floats2half2_rn(o0, o1);
            hp[1] = __floats2half2_rn(o2, o3);
        }
    }
}

// ---------------- CSR pass 2: one 256-thread block per bucket ----------------
__global__ __launch_bounds__(256) void k_local_csr(
    const int* __restrict__ bucketCnt, const unsigned int* __restrict__ ebuf,
    int* __restrict__ row_ptr, int* __restrict__ esrc){
    __shared__ int deg[256];
    __shared__ int scn[256];
    __shared__ int cntAll[NB];
    int b = blockIdx.x, t = threadIdx.x;
    deg[t] = 0;
    for (int j = t; j < NB; j += 256) cntAll[j] = bucketCnt[j];
    __syncthreads();
    // parallel bucket-prefix: sum cntAll[0..b) across all 256 threads
    int partial = 0;
    for (int j = t; j < b; j += 256) partial += cntAll[j];
    scn[t] = partial;
    __syncthreads();
    for (int off = 128; off > 0; off >>= 1){
        if (t < off) scn[t] += scn[t + off];
        __syncthreads();
    }
    int sbase = scn[0];
    int cnt = cntAll[b];
    __syncthreads();
    const unsigned int* seg = ebuf + b * BCAP;
    for (int i = t; i < cnt; i += 256)
        atomicAdd(&deg[seg[i] >> 17], 1);
    __syncthreads();
    int v = deg[t];
    scn[t] = v;
    __syncthreads();
    for (int off = 1; off < 256; off <<= 1){
        int xx = (t >= off) ? scn[t - off] : 0;
        __syncthreads();
        scn[t] += xx;
        __syncthreads();
    }
    int excl = scn[t] - v;
    int start = sbase + excl;
    int n = b * 256 + t;
    if (n < N_NODES) row_ptr[n] = start;
    if (b == NB - 1 && t == 0) row_ptr[N_NODES] = sbase + cnt;
    deg[t] = start;            // reuse as global cursor
    __syncthreads();
    for (int i = t; i < cnt; i += 256){
        unsigned int e = seg[i];
        int pos = atomicAdd(&deg[e >> 17], 1);
        esrc[pos] = (int)(e & 0x1FFFFu);
    }
}

// ---------------- Layer 1 aggregate: 4 edge-groups x 16 lanes x 8 dims, fp16 pk-acc, unroll 4 ----------------
__global__ __launch_bounds__(256) void k_agg1(
    const __half* __restrict__ h1h, const float* __restrict__ a_s1, const float* __restrict__ a_d1,
    const int* __restrict__ row_ptr, const int* __restrict__ esrc,
    const float* __restrict__ b1, __half* __restrict__ hL1h){
    int t = threadIdx.x;
    int wv = t >> 6, lane = t & 63;
    int n = blockIdx.x * 4 + wv;               // N divisible by 4
    int g = lane >> 4;                          // edge subgroup (0..3)
    int l = lane & 15;                          // owns dims 8l..8l+7
    int hd = l >> 2;                            // head for these dims

    float adh = a_d1[(unsigned)(n * 4 + hd)];
    float den = 0.f;
    __half2 zero2 = __float2half2_rn(0.f);
    __half2 acc[4] = {zero2, zero2, zero2, zero2};
    const __half* hb = h1h + ((unsigned)l << 3);   // lane's slice base

    if (g == 0){
        // self-loop (softmax shift m=0: logits are O(1); acc scaled by 1/16 for fp16 range)
        float w = __expf(leaky(a_s1[(unsigned)(n * 4 + hd)] + adh));
        den = w;
        uint4 r = *(const uint4*)(hb + ((unsigned)n << 7));
        pkfma4(acc, __float2half2_rn(w * 0.0625f), r);
    }
    int start = row_ptr[n], end = row_ptr[n + 1];
    int len = end - start;
    int chunk = (len + 3) >> 2;
    int i = start + g * chunk;
    int e = i + chunk; if (e > end) e = end;
    for (; i + 3 < e; i += 4){
        int s0 = esrc[i], s1 = esrc[i + 1], s2 = esrc[i + 2], s3 = esrc[i + 3];
        float a0 = a_s1[(unsigned)(s0 * 4 + hd)];
        float a1 = a_s1[(unsigned)(s1 * 4 + hd)];
        float a2 = a_s1[(unsigned)(s2 * 4 + hd)];
        float a3 = a_s1[(unsigned)(s3 * 4 + hd)];
        uint4 r0 = *(const uint4*)(hb + ((unsigned)s0 << 7));
        uint4 r1 = *(const uint4*)(hb + ((unsigned)s1 << 7));
        uint4 r2 = *(const uint4*)(hb + ((unsigned)s2 << 7));
        uint4 r3 = *(const uint4*)(hb + ((unsigned)s3 << 7));
        float w0 = __expf(leaky(a0 + adh));
        float w1 = __expf(leaky(a1 + adh));
        float w2 = __expf(leaky(a2 + adh));
        float w3 = __expf(leaky(a3 + adh));
        den += (w0 + w1) + (w2 + w3);
        pkfma4(acc, __float2half2_rn(w0 * 0.0625f), r0);
        pkfma4(acc, __float2half2_rn(w1 * 0.0625f), r1);
        pkfma4(acc, __float2half2_rn(w2 * 0.0625f), r2);
        pkfma4(acc, __float2half2_rn(w3 * 0.0625f), r3);
    }
    for (; i < e; i++){
        int s0 = esrc[i];
        float w0 = __expf(leaky(a_s1[(unsigned)(s0 * 4 + hd)] + adh));
        uint4 r0 = *(const uint4*)(hb + ((unsigned)s0 << 7));
        den += w0;
        pkfma4(acc, __float2half2_rn(w0 * 0.0625f), r0);
    }
    // combine the four edge-groups (lanes xor16/xor32 share l, hd)
    den += __shfl_xor(den, 16); den += __shfl_xor(den, 32);
    #pragma unroll
    for (int k = 0; k < 4; k++){
        acc[k] = __hadd2(acc[k], shfl_xor_h2(acc[k], 16));
        acc[k] = __hadd2(acc[k], shfl_xor_h2(acc[k], 32));
    }
    if (g == 0){
        float inv = 16.f / (den + 1e-16f);      // x16 undoes the 1/16 acc scaling
        int d0 = l * 8;
        float4 ba = *(const float4*)(b1 + d0);
        float4 bb = *(const float4*)(b1 + d0 + 4);
        float2 f0 = __half22float2(acc[0]);
        float2 f1 = __half22float2(acc[1]);
        float2 f2 = __half22float2(acc[2]);
        float2 f3 = __half22float2(acc[3]);
        __half2 o[4];
        o[0] = __floats2half2_rn(elu1(f0.x * inv + ba.x), elu1(f0.y * inv + ba.y));
        o[1] = __floats2half2_rn(elu1(f1.x * inv + ba.z), elu1(f1.y * inv + ba.w));
        o[2] = __floats2half2_rn(elu1(f2.x * inv + bb.x), elu1(f2.y * inv + bb.y));
        o[3] = __floats2half2_rn(elu1(f3.x * inv + bb.z), elu1(f3.y * inv + bb.w));
        *(uint4*)(hL1h + (size_t)n * F1 + d0) = *(uint4*)o;
    }
}

// ---------------- Layer 2 dense: 80 nodes/block (W2 staged once); fp16 in/out ----------------
__global__ __launch_bounds__(256) void k_dense2(
    const __half* __restrict__ hL1h, const float* __restrict__ W2,
    const float* __restrict__ as2w, const float* __restrict__ ad2w,
    __half* __restrict__ h2h, float* __restrict__ a_s2, float* __restrict__ a_d2){
    __shared__ float W2s[F1 * F2];     // 8 KB
    __shared__ __half hs[16 * F1];     // 4 KB
    int t = threadIdx.x;
    ((float4*)W2s)[t]       = ((const float4*)W2)[t];
    ((float4*)W2s)[t + 256] = ((const float4*)W2)[t + 256];
    int ln = t >> 4, dim = t & 15;
    float asw = as2w[dim], adw = ad2w[dim];
    #pragma unroll
    for (int it = 0; it < 5; it++){
        __syncthreads();
        ((uint4*)hs)[t] = ((const uint4*)(hL1h + ((size_t)blockIdx.x * 80 + it * 16) * F1))[t];
        __syncthreads();
        int n = blockIdx.x * 80 + it * 16 + ln;
        float dot = 0.f;
        const __half2* hrow = (const __half2*)(hs + ln * F1);
        #pragma unroll 8
        for (int k2 = 0; k2 < 64; k2++){
            float2 f = __half22float2(hrow[k2]);
            dot += f.x * W2s[(2 * k2) * 16 + dim];
            dot += f.y * W2s[(2 * k2 + 1) * 16 + dim];
        }
        float ps = dot * asw;
        float pd = dot * adw;
        #pragma unroll
        for (int off = 8; off >= 1; off >>= 1){
            ps += __shfl_down(ps, off, 16);
            pd += __shfl_down(pd, off, 16);
        }
        if (dim == 0){ a_s2[n] = ps; a_d2[n] = pd; }
        h2h[(size_t)n * 16 + dim] = __float2half(dot);
    }
}

// ---------------- Layer 2 aggregate + classifier: 8 edge-groups x 8 lanes x 2 dims, unroll 4 ----------------
__global__ __launch_bounds__(256) void k_agg2(
    const __half* __restrict__ h2h, const float* __restrict__ a_s2, const float* __restrict__ a_d2,
    const int* __restrict__ row_ptr, const int* __restrict__ esrc,
    const float* __restrict__ b2, const float* __restrict__ Wc1, const float* __restrict__ bc1,
    const float* __restrict__ Wc2, const float* __restrict__ bc2, float* __restrict__ out){
    int t = threadIdx.x;
    int wv = t >> 6, lane = t & 63;
    int n = blockIdx.x * 4 + wv;       // N divisible by 4
    int g = lane >> 3;                 // edge subgroup (0..7)
    int l = lane & 7;                  // owns dims 2l, 2l+1
    float adn = a_d2[n];
    const __half* hb2 = h2h + 2 * l;

    float den = 0.f, acc0 = 0.f, acc1 = 0.f;
    if (g == 0){
        float w = __expf(leaky(a_s2[n] + adn));
        den = w;
        float2 f = __half22float2(*(const __half2*)(hb2 + ((unsigned)n << 4)));
        acc0 = w * f.x; acc1 = w * f.y;
    }
    int start = row_ptr[n], end = row_ptr[n + 1];
    int len = end - start;
    int chunk = (len + 7) >> 3;
    int i = start + g * chunk;
    int e = i + chunk; if (e > end) e = end;
    for (; i + 3 < e; i += 4){
        int s0 = esrc[i], s1 = esrc[i + 1], s2 = esrc[i + 2], s3 = esrc[i + 3];
        float a0 = a_s2[s0], a1 = a_s2[s1], a2 = a_s2[s2], a3 = a_s2[s3];
        __half2 p0 = *(const __half2*)(hb2 + ((unsigned)s0 << 4));
        __half2 p1 = *(const __half2*)(hb2 + ((unsigned)s1 << 4));
        __half2 p2 = *(const __half2*)(hb2 + ((unsigned)s2 << 4));
        __half2 p3 = *(const __half2*)(hb2 + ((unsigned)s3 << 4));
        float w0 = __expf(leaky(a0 + adn));
        float w1 = __expf(leaky(a1 + adn));
        float w2 = __expf(leaky(a2 + adn));
        float w3 = __expf(leaky(a3 + adn));
        den += (w0 + w1) + (w2 + w3);
        float2 f0 = __half22float2(p0), f1 = __half22float2(p1);
        float2 f2 = __half22float2(p2), f3 = __half22float2(p3);
        acc0 += w0 * f0.x + w1 * f1.x + w2 * f2.x + w3 * f3.x;
        acc1 += w0 * f0.y + w1 * f1.y + w2 * f2.y + w3 * f3.y;
    }
    for (; i < e; i++){
        int s0 = esrc[i];
        float w0 = __expf(leaky(a_s2[s0] + adn));
        float2 f0 = __half22float2(*(const __half2*)(hb2 + ((unsigned)s0 << 4)));
        den += w0;
        acc0 += w0 * f0.x; acc1 += w0 * f0.y;
    }
    #pragma unroll
    for (int off = 8; off <= 32; off <<= 1){
        den  += __shfl_xor(den, off);
        acc0 += __shfl_xor(acc0, off);
        acc1 += __shfl_xor(acc1, off);
    }
    float inv = 1.f / (den + 1e-16f);
    float e0v = elu1(acc0 * inv + b2[2 * l]);
    float e1v = elu1(acc1 * inv + b2[2 * l + 1]);
    if (g == 0){
        float2 ov; ov.x = e0v; ov.y = e1v;
        *(float2*)(out + (size_t)n * 16 + 2 * l) = ov;
    }
    // classifier: each 8-lane cluster computes the full hidden layer redundantly
    float hid = bc1[l];
    #pragma unroll
    for (int j = 0; j < 8; j++){
        float a = __shfl(e0v, j, 8);
        float b = __shfl(e1v, j, 8);
        hid += a * Wc1[(2 * j) * 8 + l] + b * Wc1[(2 * j + 1) * 8 + l];
    }
    float contrib = fmaxf(hid, 0.f) * Wc2[l];
    contrib += __shfl_xor(contrib, 1);
    contrib += __shfl_xor(contrib, 2);
    contrib += __shfl_xor(contrib, 4);
    if (lane == 0) out[(size_t)N_NODES * 16 + n] = 1.f / (1.f + __expf(-(contrib + bc2[0])));
}

extern "C" void kernel_launch(void* const* d_in, const int* in_sizes, int n_in,
                              void* d_out, int out_size, void* d_ws, size_t ws_size,
                              hipStream_t stream){
    const float* x    = (const float*)d_in[0];
    const int*   ei   = (const int*)d_in[1];
    const float* W1   = (const float*)d_in[2];
    const float* as1w = (const float*)d_in[3];
    const float* ad1w = (const float*)d_in[4];
    const float* b1   = (const float*)d_in[5];
    const float* W2   = (const float*)d_in[6];
    const float* as2w = (const float*)d_in[7];
    const float* ad2w = (const float*)d_in[8];
    const float* b2   = (const float*)d_in[9];
    const float* Wc1  = (const float*)d_in[10];
    const float* bc1  = (const float*)d_in[11];
    const float* Wc2  = (const float*)d_in[12];
    const float* bc2  = (const float*)d_in[13];
    float* out = (float*)d_out;
    const int* src = ei;
    const int* dst = ei + N_EDGES;

    float* ws   = (float*)d_ws;
    float* a_s1 = ws;                                   // N*4
    float* a_d1 = a_s1 + (size_t)N_NODES * 4;           // N*4
    float* a_s2 = a_d1 + (size_t)N_NODES * 4;           // N
    float* a_d2 = a_s2 + N_NODES;                       // N
    __half* h1h  = (__half*)(a_d2 + N_NODES);           // N*128 f16
    __half* hL1h = h1h + (size_t)N_NODES * F1;          // N*128 f16
    __half* h2h  = hL1h + (size_t)N_NODES * F1;         // N*16 f16
    int* bucketCnt = (int*)(h2h + (size_t)N_NODES * 16);// NB
    int* row_ptr  = bucketCnt + NB;                     // N+1
    int* esrc     = row_ptr + N_NODES + 1;              // E
    unsigned int* ebuf = (unsigned int*)(esrc + N_EDGES); // NB*BCAP

    hipMemsetAsync(bucketCnt, 0, NB * sizeof(int), stream);
    k_build_dense1<<<NBLK_BIN + NBLK_D1, 256, 0, stream>>>(
        src, dst, bucketCnt, ebuf, x, W1, as1w, ad1w, h1h, a_s1, a_d1);
    k_local_csr<<<NB, 256, 0, stream>>>(bucketCnt, ebuf, row_ptr, esrc);
    k_agg1<<<N_NODES / 4, 256, 0, stream>>>(h1h, a_s1, a_d1, row_ptr, esrc, b1, hL1h);
    k_dense2<<<N_NODES / 80, 256, 0, stream>>>(hL1h, W2, as2w, ad2w, h2h, a_s2, a_d2);
    k_agg2<<<N_NODES / 4, 256, 0, stream>>>(h2h, a_s2, a_d2, row_ptr, esrc, b2, Wc1, bc1, Wc2, bc2, out);
}

// Round 13
// 283.298 us; speedup vs baseline: 1.0032x; 1.0032x over previous
//
#include <hip/hip_runtime.h>
#include <hip/hip_fp16.h>
#include <math.h>

#define N_NODES 100000
#define N_EDGES 1600000
#define F_IN 8
#define HID 32
#define HEADS 4
#define F1 128    // HEADS*HID
#define F2 16     // OUT
#define NB 782          // buckets of 128 nodes  ((100000+127)/128)
#define NBLK_BIN 391    // edge-binning blocks of 4096 edges
#define BCAP 2688       // per-bucket capacity (mean ~2046, sd ~45 -> 14 sigma)

__device__ __forceinline__ float leaky(float x){ return x > 0.f ? x : 0.2f * x; }
__device__ __forceinline__ float elu1(float x){ return x > 0.f ? x : __expf(x) - 1.f; }

__device__ __forceinline__ __half2 shfl_xor_h2(__half2 v, int m){
    int iv = *(int*)&v;
    iv = __shfl_xor(iv, m);
    return *(__half2*)&iv;
}

// fp16 packed FMA of one 16B slice (8 halves) into 4 half2 accumulators
__device__ __forceinline__ void pkfma4(__half2* acc, __half2 w2, const uint4& r){
    const __half2* p = (const __half2*)&r;
    #pragma unroll
    for (int k = 0; k < 4; k++) acc[k] = __hfma2(w2, p[k], acc[k]);
}

// ---------------- Fused: edge binning (blocks 0..390) + layer-1 dense (rest) ----------------
__global__ __launch_bounds__(256) void k_build_dense1(
    const int* __restrict__ src, const int* __restrict__ dst,
    int* __restrict__ bucketCnt, unsigned int* __restrict__ ebuf,
    const float* __restrict__ x, const float* __restrict__ W1,
    const float* __restrict__ as1w, const float* __restrict__ ad1w,
    __half* __restrict__ h1h, float* __restrict__ a_s1, float* __restrict__ a_d1){
    __shared__ __align__(16) char smem_raw[9408];
    int t = threadIdx.x;
    if (blockIdx.x < NBLK_BIN){
        // ---- edge binning: 4096 edges -> 782 coarse buckets (128 nodes), line-local writes ----
        int* hist    = (int*)smem_raw;       // NB
        int* basePos = hist + NB;            // NB
        int* cur     = basePos + NB;         // NB
        for (int j = t; j < NB; j += 256) hist[j] = 0;
        __syncthreads();
        int base = blockIdx.x * 4096;
        int dv[16];                        // register-cache dst (skip re-read in scatter pass)
        #pragma unroll
        for (int j = 0; j < 16; j++){
            int e = base + j * 256 + t;
            dv[j] = (e < N_EDGES) ? dst[e] : -1;
            if (dv[j] >= 0) atomicAdd(&hist[dv[j] >> 7], 1);
        }
        __syncthreads();
        for (int j = t; j < NB; j += 256){
            int h = hist[j];
            if (h) basePos[j] = atomicAdd(&bucketCnt[j], h);
            cur[j] = 0;
        }
        __syncthreads();
        #pragma unroll
        for (int j = 0; j < 16; j++){
            if (dv[j] >= 0){
                int e = base + j * 256 + t;
                int d = dv[j];
                int b = d >> 7;
                int off = atomicAdd(&cur[b], 1);
                ebuf[b * BCAP + basePos[b] + off] = ((unsigned)(d & 127) << 17) | (unsigned)src[e];
            }
        }
    } else {
        // ---- layer-1 dense: h1 = x@W1 (fp16 out); per-head attention dots ----
        float* W1s  = (float*)smem_raw;      // 1024
        float* atts = W1s + 1024;            // 128
        float* attd = atts + 128;            // 128
        float* xs   = attd + 128;            // 64
        int bid = blockIdx.x - NBLK_BIN;
        ((float4*)W1s)[t] = ((const float4*)W1)[t];
        if (t < 128){ atts[t] = as1w[t]; attd[t] = ad1w[t]; }
        if (t < 64) xs[t] = x[bid * 64 + t];
        __syncthreads();

        int ln = t >> 5, l32 = t & 31;
        int n = bid * 8 + ln;               // N divisible by 8
        float xr[8];
        #pragma unroll
        for (int k = 0; k < 8; k++) xr[k] = xs[ln * 8 + k];
        int j0 = l32 * 4;
        float o0 = 0, o1 = 0, o2 = 0, o3 = 0;
        #pragma unroll
        for (int k = 0; k < 8; k++){
            float4 w4 = ((const float4*)(W1s + k * F1))[l32];
            o0 += xr[k] * w4.x; o1 += xr[k] * w4.y; o2 += xr[k] * w4.z; o3 += xr[k] * w4.w;
        }
        int hd = l32 >> 3;
        int dl = j0 & 31;
        float ps = o0 * atts[hd * 32 + dl] + o1 * atts[hd * 32 + dl + 1]
                 + o2 * atts[hd * 32 + dl + 2] + o3 * atts[hd * 32 + dl + 3];
        float pd = o0 * attd[hd * 32 + dl] + o1 * attd[hd * 32 + dl + 1]
                 + o2 * attd[hd * 32 + dl + 2] + o3 * attd[hd * 32 + dl + 3];
        ps += __shfl_down(ps, 4, 8); ps += __shfl_down(ps, 2, 8); ps += __shfl_down(ps, 1, 8);
        pd += __shfl_down(pd, 4, 8); pd += __shfl_down(pd, 2, 8); pd += __shfl_down(pd, 1, 8);
        if ((l32 & 7) == 0){ a_s1[n * 4 + hd] = ps; a_d1[n * 4 + hd] = pd; }
        __half2* hp = (__half2*)(h1h + (size_t)n * F1 + j0);
        hp[0] = __floats2half2_rn(o0, o1);
        hp[1] = __floats2half2_rn(o2, o3);
    }
}

// ---------------- CSR pass 2: one 256-thread block per 128-node bucket ----------------
__global__ __launch_bounds__(256) void k_local_csr(
    const int* __restrict__ bucketCnt, const unsigned int* __restrict__ ebuf,
    int* __restrict__ row_ptr, int* __restrict__ esrc){
    __shared__ int deg[128];
    __shared__ int scn[256];
    __shared__ int cntAll[NB];
    int b = blockIdx.x, t = threadIdx.x;
    if (t < 128) deg[t] = 0;
    for (int j = t; j < NB; j += 256) cntAll[j] = bucketCnt[j];
    __syncthreads();
    // parallel bucket-prefix: sum cntAll[0..b) across all 256 threads
    int partial = 0;
    for (int j = t; j < b; j += 256) partial += cntAll[j];
    scn[t] = partial;
    __syncthreads();
    for (int off = 128; off > 0; off >>= 1){
        if (t < off) scn[t] += scn[t + off];
        __syncthreads();
    }
    int sbase = scn[0];
    int cnt = cntAll[b];
    __syncthreads();
    const unsigned int* seg = ebuf + b * BCAP;
    for (int i = t; i < cnt; i += 256)
        atomicAdd(&deg[seg[i] >> 17], 1);
    __syncthreads();
    // Hillis-Steele inclusive scan over 128 node degrees
    int v = (t < 128) ? deg[t] : 0;
    scn[t] = v;
    __syncthreads();
    for (int off = 1; off < 128; off <<= 1){
        int xx = (t >= off && t < 128) ? scn[t - off] : 0;
        __syncthreads();
        if (t < 128) scn[t] += xx;
        __syncthreads();
    }
    if (t < 128){
        int excl = scn[t] - v;
        int start = sbase + excl;
        int n = b * 128 + t;
        if (n < N_NODES) row_ptr[n] = start;
        if (b == NB - 1 && t == 0) row_ptr[N_NODES] = sbase + cnt;
        deg[t] = start;            // reuse as global cursor
    }
    __syncthreads();
    for (int i = t; i < cnt; i += 256){
        unsigned int e = seg[i];
        int pos = atomicAdd(&deg[e >> 17], 1);
        esrc[pos] = (int)(e & 0x1FFFFu);
    }
}

// ---------------- Layer 1 aggregate: 4 edge-groups x 16 lanes x 8 dims, fp16 pk-acc, unroll 4 ----------------
__global__ __launch_bounds__(256) void k_agg1(
    const __half* __restrict__ h1h, const float* __restrict__ a_s1, const float* __restrict__ a_d1,
    const int* __restrict__ row_ptr, const int* __restrict__ esrc,
    const float* __restrict__ b1, __half* __restrict__ hL1h){
    int t = threadIdx.x;
    int wv = t >> 6, lane = t & 63;
    int n = blockIdx.x * 4 + wv;               // N divisible by 4
    int g = lane >> 4;                          // edge subgroup (0..3)
    int l = lane & 15;                          // owns dims 8l..8l+7
    int hd = l >> 2;                            // head for these dims

    float adh = a_d1[(unsigned)(n * 4 + hd)];
    float den = 0.f;
    __half2 zero2 = __float2half2_rn(0.f);
    __half2 acc[4] = {zero2, zero2, zero2, zero2};
    const __half* hb = h1h + ((unsigned)l << 3);   // lane's slice base

    if (g == 0){
        // self-loop (softmax shift m=0: logits are O(1); acc scaled by 1/16 for fp16 range)
        float w = __expf(leaky(a_s1[(unsigned)(n * 4 + hd)] + adh));
        den = w;
        uint4 r = *(const uint4*)(hb + ((unsigned)n << 7));
        pkfma4(acc, __float2half2_rn(w * 0.0625f), r);
    }
    int start = row_ptr[n], end = row_ptr[n + 1];
    int len = end - start;
    int chunk = (len + 3) >> 2;
    int i = start + g * chunk;
    int e = i + chunk; if (e > end) e = end;
    for (; i + 3 < e; i += 4){
        int s0 = esrc[i], s1 = esrc[i + 1], s2 = esrc[i + 2], s3 = esrc[i + 3];
        float a0 = a_s1[(unsigned)(s0 * 4 + hd)];
        float a1 = a_s1[(unsigned)(s1 * 4 + hd)];
        float a2 = a_s1[(unsigned)(s2 * 4 + hd)];
        float a3 = a_s1[(unsigned)(s3 * 4 + hd)];
        uint4 r0 = *(const uint4*)(hb + ((unsigned)s0 << 7));
        uint4 r1 = *(const uint4*)(hb + ((unsigned)s1 << 7));
        uint4 r2 = *(const uint4*)(hb + ((unsigned)s2 << 7));
        uint4 r3 = *(const uint4*)(hb + ((unsigned)s3 << 7));
        float w0 = __expf(leaky(a0 + adh));
        float w1 = __expf(leaky(a1 + adh));
        float w2 = __expf(leaky(a2 + adh));
        float w3 = __expf(leaky(a3 + adh));
        den += (w0 + w1) + (w2 + w3);
        pkfma4(acc, __float2half2_rn(w0 * 0.0625f), r0);
        pkfma4(acc, __float2half2_rn(w1 * 0.0625f), r1);
        pkfma4(acc, __float2half2_rn(w2 * 0.0625f), r2);
        pkfma4(acc, __float2half2_rn(w3 * 0.0625f), r3);
    }
    for (; i < e; i++){
        int s0 = esrc[i];
        float w0 = __expf(leaky(a_s1[(unsigned)(s0 * 4 + hd)] + adh));
        uint4 r0 = *(const uint4*)(hb + ((unsigned)s0 << 7));
        den += w0;
        pkfma4(acc, __float2half2_rn(w0 * 0.0625f), r0);
    }
    // combine the four edge-groups (lanes xor16/xor32 share l, hd)
    den += __shfl_xor(den, 16); den += __shfl_xor(den, 32);
    #pragma unroll
    for (int k = 0; k < 4; k++){
        acc[k] = __hadd2(acc[k], shfl_xor_h2(acc[k], 16));
        acc[k] = __hadd2(acc[k], shfl_xor_h2(acc[k], 32));
    }
    if (g == 0){
        float inv = 16.f / (den + 1e-16f);      // x16 undoes the 1/16 acc scaling
        int d0 = l * 8;
        float4 ba = *(const float4*)(b1 + d0);
        float4 bb = *(const float4*)(b1 + d0 + 4);
        float2 f0 = __half22float2(acc[0]);
        float2 f1 = __half22float2(acc[1]);
        float2 f2 = __half22float2(acc[2]);
        float2 f3 = __half22float2(acc[3]);
        __half2 o[4];
        o[0] = __floats2half2_rn(elu1(f0.x * inv + ba.x), elu1(f0.y * inv + ba.y));
        o[1] = __floats2half2_rn(elu1(f1.x * inv + ba.z), elu1(f1.y * inv + ba.w));
        o[2] = __floats2half2_rn(elu1(f2.x * inv + bb.x), elu1(f2.y * inv + bb.y));
        o[3] = __floats2half2_rn(elu1(f3.x * inv + bb.z), elu1(f3.y * inv + bb.w));
        *(uint4*)(hL1h + (size_t)n * F1 + d0) = *(uint4*)o;
    }
}

// ---------------- Layer 2 dense: h2 = hL1@W2 (fp16 in/out) ; a_s2/a_d2 ----------------
__global__ __launch_bounds__(256) void k_dense2(
    const __half* __restrict__ hL1h, const float* __restrict__ W2,
    const float* __restrict__ as2w, const float* __restrict__ ad2w,
    __half* __restrict__ h2h, float* __restrict__ a_s2, float* __restrict__ a_d2){
    __shared__ float W2s[F1 * F2];     // 8 KB
    __shared__ __half hs[16 * F1];     // 4 KB
    int t = threadIdx.x;
    ((float4*)W2s)[t]       = ((const float4*)W2)[t];
    ((float4*)W2s)[t + 256] = ((const float4*)W2)[t + 256];
    ((uint4*)hs)[t] = ((const uint4*)(hL1h + (size_t)blockIdx.x * 16 * F1))[t];
    __syncthreads();

    int ln = t >> 4, dim = t & 15;
    int n = blockIdx.x * 16 + ln;      // N divisible by 16
    float dot = 0.f;
    const __half2* hrow = (const __half2*)(hs + ln * F1);
    #pragma unroll 8
    for (int k2 = 0; k2 < 64; k2++){
        float2 f = __half22float2(hrow[k2]);
        dot += f.x * W2s[(2 * k2) * 16 + dim];
        dot += f.y * W2s[(2 * k2 + 1) * 16 + dim];
    }
    float ps = dot * as2w[dim];
    float pd = dot * ad2w[dim];
    #pragma unroll
    for (int off = 8; off >= 1; off >>= 1){
        ps += __shfl_down(ps, off, 16);
        pd += __shfl_down(pd, off, 16);
    }
    if (dim == 0){ a_s2[n] = ps; a_d2[n] = pd; }
    h2h[(size_t)n * 16 + dim] = __float2half(dot);
}

// ---------------- Layer 2 aggregate + classifier: 8 edge-groups x 8 lanes x 2 dims, unroll 4 ----------------
__global__ __launch_bounds__(256) void k_agg2(
    const __half* __restrict__ h2h, const float* __restrict__ a_s2, const float* __restrict__ a_d2,
    const int* __restrict__ row_ptr, const int* __restrict__ esrc,
    const float* __restrict__ b2, const float* __restrict__ Wc1, const float* __restrict__ bc1,
    const float* __restrict__ Wc2, const float* __restrict__ bc2, float* __restrict__ out){
    int t = threadIdx.x;
    int wv = t >> 6, lane = t & 63;
    int n = blockIdx.x * 4 + wv;       // N divisible by 4
    int g = lane >> 3;                 // edge subgroup (0..7)
    int l = lane & 7;                  // owns dims 2l, 2l+1
    float adn = a_d2[n];
    const __half* hb2 = h2h + 2 * l;

    float den = 0.f, acc0 = 0.f, acc1 = 0.f;
    if (g == 0){
        float w = __expf(leaky(a_s2[n] + adn));
        den = w;
        float2 f = __half22float2(*(const __half2*)(hb2 + ((unsigned)n << 4)));
        acc0 = w * f.x; acc1 = w * f.y;
    }
    int start = row_ptr[n], end = row_ptr[n + 1];
    int len = end - start;
    int chunk = (len + 7) >> 3;
    int i = start + g * chunk;
    int e = i + chunk; if (e > end) e = end;
    for (; i + 3 < e; i += 4){
        int s0 = esrc[i], s1 = esrc[i + 1], s2 = esrc[i + 2], s3 = esrc[i + 3];
        float a0 = a_s2[s0], a1 = a_s2[s1], a2 = a_s2[s2], a3 = a_s2[s3];
        __half2 p0 = *(const __half2*)(hb2 + ((unsigned)s0 << 4));
        __half2 p1 = *(const __half2*)(hb2 + ((unsigned)s1 << 4));
        __half2 p2 = *(const __half2*)(hb2 + ((unsigned)s2 << 4));
        __half2 p3 = *(const __half2*)(hb2 + ((unsigned)s3 << 4));
        float w0 = __expf(leaky(a0 + adn));
        float w1 = __expf(leaky(a1 + adn));
        float w2 = __expf(leaky(a2 + adn));
        float w3 = __expf(leaky(a3 + adn));
        den += (w0 + w1) + (w2 + w3);
        float2 f0 = __half22float2(p0), f1 = __half22float2(p1);
        float2 f2 = __half22float2(p2), f3 = __half22float2(p3);
        acc0 += w0 * f0.x + w1 * f1.x + w2 * f2.x + w3 * f3.x;
        acc1 += w0 * f0.y + w1 * f1.y + w2 * f2.y + w3 * f3.y;
    }
    for (; i < e; i++){
        int s0 = esrc[i];
        float w0 = __expf(leaky(a_s2[s0] + adn));
        float2 f0 = __half22float2(*(const __half2*)(hb2 + ((unsigned)s0 << 4)));
        den += w0;
        acc0 += w0 * f0.x; acc1 += w0 * f0.y;
    }
    #pragma unroll
    for (int off = 8; off <= 32; off <<= 1){
        den  += __shfl_xor(den, off);
        acc0 += __shfl_xor(acc0, off);
        acc1 += __shfl_xor(acc1, off);
    }
    float inv = 1.f / (den + 1e-16f);
    float e0v = elu1(acc0 * inv + b2[2 * l]);
    float e1v = elu1(acc1 * inv + b2[2 * l + 1]);
    if (g == 0){
        float2 ov; ov.x = e0v; ov.y = e1v;
        *(float2*)(out + (size_t)n * 16 + 2 * l) = ov;
    }
    // classifier: each 8-lane cluster computes the full hidden layer redundantly
    float hid = bc1[l];
    #pragma unroll
    for (int j = 0; j < 8; j++){
        float a = __shfl(e0v, j, 8);
        float b = __shfl(e1v, j, 8);
        hid += a * Wc1[(2 * j) * 8 + l] + b * Wc1[(2 * j + 1) * 8 + l];
    }
    float contrib = fmaxf(hid, 0.f) * Wc2[l];
    contrib += __shfl_xor(contrib, 1);
    contrib += __shfl_xor(contrib, 2);
    contrib += __shfl_xor(contrib, 4);
    if (lane == 0) out[(size_t)N_NODES * 16 + n] = 1.f / (1.f + __expf(-(contrib + bc2[0])));
}

extern "C" void kernel_launch(void* const* d_in, const int* in_sizes, int n_in,
                              void* d_out, int out_size, void* d_ws, size_t ws_size,
                              hipStream_t stream){
    const float* x    = (const float*)d_in[0];
    const int*   ei   = (const int*)d_in[1];
    const float* W1   = (const float*)d_in[2];
    const float* as1w = (const float*)d_in[3];
    const float* ad1w = (const float*)d_in[4];
    const float* b1   = (const float*)d_in[5];
    const float* W2   = (const float*)d_in[6];
    const float* as2w = (const float*)d_in[7];
    const float* ad2w = (const float*)d_in[8];
    const float* b2   = (const float*)d_in[9];
    const float* Wc1  = (const float*)d_in[10];
    const float* bc1  = (const float*)d_in[11];
    const float* Wc2  = (const float*)d_in[12];
    const float* bc2  = (const float*)d_in[13];
    float* out = (float*)d_out;
    const int* src = ei;
    const int* dst = ei + N_EDGES;

    float* ws   = (float*)d_ws;
    float* a_s1 = ws;                                   // N*4
    float* a_d1 = a_s1 + (size_t)N_NODES * 4;           // N*4
    float* a_s2 = a_d1 + (size_t)N_NODES * 4;           // N
    float* a_d2 = a_s2 + N_NODES;                       // N
    __half* h1h  = (__half*)(a_d2 + N_NODES);           // N*128 f16
    __half* hL1h = h1h + (size_t)N_NODES * F1;          // N*128 f16
    __half* h2h  = hL1h + (size_t)N_NODES * F1;         // N*16 f16
    int* bucketCnt = (int*)(h2h + (size_t)N_NODES * 16);// NB
    int* row_ptr  = bucketCnt + NB;                     // N+1
    int* esrc     = row_ptr + N_NODES + 1;              // E
    unsigned int* ebuf = (unsigned int*)(esrc + N_EDGES); // NB*BCAP

    hipMemsetAsync(bucketCnt, 0, NB * sizeof(int), stream);
    k_build_dense1<<<NBLK_BIN + N_NODES / 8, 256, 0, stream>>>(
        src, dst, bucketCnt, ebuf, x, W1, as1w, ad1w, h1h, a_s1, a_d1);
    k_local_csr<<<NB, 256, 0, stream>>>(bucketCnt, ebuf, row_ptr, esrc);
    k_agg1<<<N_NODES / 4, 256, 0, stream>>>(h1h, a_s1, a_d1, row_ptr, esrc, b1, hL1h);
    k_dense2<<<N_NODES / 16, 256, 0, stream>>>(hL1h, W2, as2w, ad2w, h2h, a_s2, a_d2);
    k_agg2<<<N_NODES / 4, 256, 0, stream>>>(h2h, a_s2, a_d2, row_ptr, esrc, b2, Wc1, bc1, Wc2, bc2, out);
}

// Round 14
// 282.598 us; speedup vs baseline: 1.0057x; 1.0025x over previous
//
#include <hip/hip_runtime.h>
#include <hip/hip_fp16.h>
#include <math.h>

#define N_NODES 100000
#define N_EDGES 1600000
#define F_IN 8
#define HID 32
#define HEADS 4
#define F1 128    // HEADS*HID
#define F2 16     // OUT
#define NB 391          // buckets of 256 nodes
#define NBLK_BIN 391    // edge-binning blocks of 4096 edges
#define BCAP 4864       // per-bucket capacity (mean 4092, sd ~64 -> 12 sigma)

__device__ __forceinline__ float leaky(float x){ return x > 0.f ? x : 0.2f * x; }
__device__ __forceinline__ float elu1(float x){ return x > 0.f ? x : __expf(x) - 1.f; }

__device__ __forceinline__ __half2 shfl_xor_h2(__half2 v, int m){
    int iv = *(int*)&v;
    iv = __shfl_xor(iv, m);
    return *(__half2*)&iv;
}

// fp16 packed FMA of one 16B slice (8 halves) into 4 half2 accumulators
__device__ __forceinline__ void pkfma4(__half2* acc, __half2 w2, const uint4& r){
    const __half2* p = (const __half2*)&r;
    #pragma unroll
    for (int k = 0; k < 4; k++) acc[k] = __hfma2(w2, p[k], acc[k]);
}

// ---------------- Fused: edge binning (blocks 0..390) + layer-1 dense (rest) ----------------
__global__ __launch_bounds__(256) void k_build_dense1(
    const int* __restrict__ src, const int* __restrict__ dst,
    int* __restrict__ bucketCnt, unsigned int* __restrict__ ebuf,
    const float* __restrict__ x, const float* __restrict__ W1,
    const float* __restrict__ as1w, const float* __restrict__ ad1w,
    __half* __restrict__ h1h, float* __restrict__ a_s1, float* __restrict__ a_d1){
    __shared__ float smem[1344];
    int t = threadIdx.x;
    if (blockIdx.x < NBLK_BIN){
        // ---- edge binning: 4096 edges -> 391 coarse buckets, line-local writes ----
        int* hist    = (int*)smem;
        int* basePos = hist + NB;
        int* cur     = basePos + NB;
        for (int j = t; j < NB; j += 256) hist[j] = 0;
        __syncthreads();
        int base = blockIdx.x * 4096;
        int dv[16];                        // register-cache dst (skip re-read in scatter pass)
        #pragma unroll
        for (int j = 0; j < 16; j++){
            int e = base + j * 256 + t;
            dv[j] = (e < N_EDGES) ? dst[e] : -1;
            if (dv[j] >= 0) atomicAdd(&hist[dv[j] >> 8], 1);
        }
        __syncthreads();
        for (int j = t; j < NB; j += 256){
            int h = hist[j];
            if (h) basePos[j] = atomicAdd(&bucketCnt[j], h);
            cur[j] = 0;
        }
        __syncthreads();
        #pragma unroll
        for (int j = 0; j < 16; j++){
            if (dv[j] >= 0){
                int e = base + j * 256 + t;
                int d = dv[j];
                int b = d >> 8;
                int off = atomicAdd(&cur[b], 1);
                ebuf[b * BCAP + basePos[b] + off] = ((unsigned)(d & 255) << 17) | (unsigned)src[e];
            }
        }
    } else {
        // ---- layer-1 dense: h1 = x@W1 (fp16 out); per-head attention dots ----
        float* W1s  = smem;          // 1024
        float* atts = smem + 1024;   // 128
        float* attd = smem + 1152;   // 128
        float* xs   = smem + 1280;   // 64
        int bid = blockIdx.x - NBLK_BIN;
        ((float4*)W1s)[t] = ((const float4*)W1)[t];
        if (t < 128){ atts[t] = as1w[t]; attd[t] = ad1w[t]; }
        if (t < 64) xs[t] = x[bid * 64 + t];
        __syncthreads();

        int ln = t >> 5, l32 = t & 31;
        int n = bid * 8 + ln;               // N divisible by 8
        float xr[8];
        #pragma unroll
        for (int k = 0; k < 8; k++) xr[k] = xs[ln * 8 + k];
        int j0 = l32 * 4;
        float o0 = 0, o1 = 0, o2 = 0, o3 = 0;
        #pragma unroll
        for (int k = 0; k < 8; k++){
            float4 w4 = ((const float4*)(W1s + k * F1))[l32];
            o0 += xr[k] * w4.x; o1 += xr[k] * w4.y; o2 += xr[k] * w4.z; o3 += xr[k] * w4.w;
        }
        int hd = l32 >> 3;
        int dl = j0 & 31;
        float ps = o0 * atts[hd * 32 + dl] + o1 * atts[hd * 32 + dl + 1]
                 + o2 * atts[hd * 32 + dl + 2] + o3 * atts[hd * 32 + dl + 3];
        float pd = o0 * attd[hd * 32 + dl] + o1 * attd[hd * 32 + dl + 1]
                 + o2 * attd[hd * 32 + dl + 2] + o3 * attd[hd * 32 + dl + 3];
        ps += __shfl_down(ps, 4, 8); ps += __shfl_down(ps, 2, 8); ps += __shfl_down(ps, 1, 8);
        pd += __shfl_down(pd, 4, 8); pd += __shfl_down(pd, 2, 8); pd += __shfl_down(pd, 1, 8);
        if ((l32 & 7) == 0){ a_s1[n * 4 + hd] = ps; a_d1[n * 4 + hd] = pd; }
        __half2* hp = (__half2*)(h1h + (size_t)n * F1 + j0);
        hp[0] = __floats2half2_rn(o0, o1);
        hp[1] = __floats2half2_rn(o2, o3);
    }
}

// ---------------- CSR pass 2: one 256-thread block per bucket ----------------
__global__ __launch_bounds__(256) void k_local_csr(
    const int* __restrict__ bucketCnt, const unsigned int* __restrict__ ebuf,
    int* __restrict__ row_ptr, int* __restrict__ esrc){
    __shared__ int deg[256];
    __shared__ int scn[256];
    __shared__ int cntAll[NB];
    int b = blockIdx.x, t = threadIdx.x;
    deg[t] = 0;
    for (int j = t; j < NB; j += 256) cntAll[j] = bucketCnt[j];
    __syncthreads();
    // parallel bucket-prefix: sum cntAll[0..b) across all 256 threads
    int partial = 0;
    for (int j = t; j < b; j += 256) partial += cntAll[j];
    scn[t] = partial;
    __syncthreads();
    for (int off = 128; off > 0; off >>= 1){
        if (t < off) scn[t] += scn[t + off];
        __syncthreads();
    }
    int sbase = scn[0];
    int cnt = cntAll[b];
    __syncthreads();
    const unsigned int* seg = ebuf + b * BCAP;
    for (int i = t; i < cnt; i += 256)
        atomicAdd(&deg[seg[i] >> 17], 1);
    __syncthreads();
    int v = deg[t];
    scn[t] = v;
    __syncthreads();
    for (int off = 1; off < 256; off <<= 1){
        int xx = (t >= off) ? scn[t - off] : 0;
        __syncthreads();
        scn[t] += xx;
        __syncthreads();
    }
    int excl = scn[t] - v;
    int start = sbase + excl;
    int n = b * 256 + t;
    if (n < N_NODES) row_ptr[n] = start;
    if (b == NB - 1 && t == 0) row_ptr[N_NODES] = sbase + cnt;
    deg[t] = start;            // reuse as global cursor
    __syncthreads();
    for (int i = t; i < cnt; i += 256){
        unsigned int e = seg[i];
        int pos = atomicAdd(&deg[e >> 17], 1);
        esrc[pos] = (int)(e & 0x1FFFFu);
    }
}

// ---------------- Layer 1 aggregate: 4 edge-groups x 16 lanes x 8 dims, fp16 pk-acc, unroll 4 ----------------
__global__ __launch_bounds__(256) void k_agg1(
    const __half* __restrict__ h1h, const float* __restrict__ a_s1, const float* __restrict__ a_d1,
    const int* __restrict__ row_ptr, const int* __restrict__ esrc,
    const float* __restrict__ b1, __half* __restrict__ hL1h){
    int t = threadIdx.x;
    int wv = t >> 6, lane = t & 63;
    int n = blockIdx.x * 4 + wv;               // N divisible by 4
    int g = lane >> 4;                          // edge subgroup (0..3)
    int l = lane & 15;                          // owns dims 8l..8l+7
    int hd = l >> 2;                            // head for these dims

    float adh = a_d1[(unsigned)(n * 4 + hd)];
    float den = 0.f;
    __half2 zero2 = __float2half2_rn(0.f);
    __half2 acc[4] = {zero2, zero2, zero2, zero2};
    const __half* hb = h1h + ((unsigned)l << 3);   // lane's slice base

    if (g == 0){
        // self-loop (softmax shift m=0: logits are O(1); acc scaled by 1/16 for fp16 range)
        float w = __expf(leaky(a_s1[(unsigned)(n * 4 + hd)] + adh));
        den = w;
        uint4 r = *(const uint4*)(hb + ((unsigned)n << 7));
        pkfma4(acc, __float2half2_rn(w * 0.0625f), r);
    }
    int start = row_ptr[n], end = row_ptr[n + 1];
    int len = end - start;
    int chunk = (len + 3) >> 2;
    int i = start + g * chunk;
    int e = i + chunk; if (e > end) e = end;
    for (; i + 3 < e; i += 4){
        int s0 = esrc[i], s1 = esrc[i + 1], s2 = esrc[i + 2], s3 = esrc[i + 3];
        float a0 = a_s1[(unsigned)(s0 * 4 + hd)];
        float a1 = a_s1[(unsigned)(s1 * 4 + hd)];
        float a2 = a_s1[(unsigned)(s2 * 4 + hd)];
        float a3 = a_s1[(unsigned)(s3 * 4 + hd)];
        uint4 r0 = *(const uint4*)(hb + ((unsigned)s0 << 7));
        uint4 r1 = *(const uint4*)(hb + ((unsigned)s1 << 7));
        uint4 r2 = *(const uint4*)(hb + ((unsigned)s2 << 7));
        uint4 r3 = *(const uint4*)(hb + ((unsigned)s3 << 7));
        float w0 = __expf(leaky(a0 + adh));
        float w1 = __expf(leaky(a1 + adh));
        float w2 = __expf(leaky(a2 + adh));
        float w3 = __expf(leaky(a3 + adh));
        den += (w0 + w1) + (w2 + w3);
        pkfma4(acc, __float2half2_rn(w0 * 0.0625f), r0);
        pkfma4(acc, __float2half2_rn(w1 * 0.0625f), r1);
        pkfma4(acc, __float2half2_rn(w2 * 0.0625f), r2);
        pkfma4(acc, __float2half2_rn(w3 * 0.0625f), r3);
    }
    for (; i < e; i++){
        int s0 = esrc[i];
        float w0 = __expf(leaky(a_s1[(unsigned)(s0 * 4 + hd)] + adh));
        uint4 r0 = *(const uint4*)(hb + ((unsigned)s0 << 7));
        den += w0;
        pkfma4(acc, __float2half2_rn(w0 * 0.0625f), r0);
    }
    // combine the four edge-groups (lanes xor16/xor32 share l, hd)
    den += __shfl_xor(den, 16); den += __shfl_xor(den, 32);
    #pragma unroll
    for (int k = 0; k < 4; k++){
        acc[k] = __hadd2(acc[k], shfl_xor_h2(acc[k], 16));
        acc[k] = __hadd2(acc[k], shfl_xor_h2(acc[k], 32));
    }
    if (g == 0){
        float inv = 16.f / (den + 1e-16f);      // x16 undoes the 1/16 acc scaling
        int d0 = l * 8;
        float4 ba = *(const float4*)(b1 + d0);
        float4 bb = *(const float4*)(b1 + d0 + 4);
        float2 f0 = __half22float2(acc[0]);
        float2 f1 = __half22float2(acc[1]);
        float2 f2 = __half22float2(acc[2]);
        float2 f3 = __half22float2(acc[3]);
        __half2 o[4];
        o[0] = __floats2half2_rn(elu1(f0.x * inv + ba.x), elu1(f0.y * inv + ba.y));
        o[1] = __floats2half2_rn(elu1(f1.x * inv + ba.z), elu1(f1.y * inv + ba.w));
        o[2] = __floats2half2_rn(elu1(f2.x * inv + bb.x), elu1(f2.y * inv + bb.y));
        o[3] = __floats2half2_rn(elu1(f3.x * inv + bb.z), elu1(f3.y * inv + bb.w));
        *(uint4*)(hL1h + (size_t)n * F1 + d0) = *(uint4*)o;
    }
}

// ---------------- Layer 2 dense: h2 = hL1@W2 (fp16 in/out) ; a_s2/a_d2 ----------------
__global__ __launch_bounds__(256) void k_dense2(
    const __half* __restrict__ hL1h, const float* __restrict__ W2,
    const float* __restrict__ as2w, const float* __restrict__ ad2w,
    __half* __restrict__ h2h, float* __restrict__ a_s2, float* __restrict__ a_d2){
    __shared__ float W2s[F1 * F2];     // 8 KB
    __shared__ __half hs[16 * F1];     // 4 KB
    int t = threadIdx.x;
    ((float4*)W2s)[t]       = ((const float4*)W2)[t];
    ((float4*)W2s)[t + 256] = ((const float4*)W2)[t + 256];
    ((uint4*)hs)[t] = ((const uint4*)(hL1h + (size_t)blockIdx.x * 16 * F1))[t];
    __syncthreads();

    int ln = t >> 4, dim = t & 15;
    int n = blockIdx.x * 16 + ln;      // N divisible by 16
    float dot = 0.f;
    const __half2* hrow = (const __half2*)(hs + ln * F1);
    #pragma unroll 8
    for (int k2 = 0; k2 < 64; k2++){
        float2 f = __half22float2(hrow[k2]);
        dot += f.x * W2s[(2 * k2) * 16 + dim];
        dot += f.y * W2s[(2 * k2 + 1) * 16 + dim];
    }
    float ps = dot * as2w[dim];
    float pd = dot * ad2w[dim];
    #pragma unroll
    for (int off = 8; off >= 1; off >>= 1){
        ps += __shfl_down(ps, off, 16);
        pd += __shfl_down(pd, off, 16);
    }
    if (dim == 0){ a_s2[n] = ps; a_d2[n] = pd; }
    h2h[(size_t)n * 16 + dim] = __float2half(dot);
}

// ---------------- Layer 2 aggregate + classifier: 8 edge-groups x 8 lanes x 2 dims, unroll 4 ----------------
__global__ __launch_bounds__(256) void k_agg2(
    const __half* __restrict__ h2h, const float* __restrict__ a_s2, const float* __restrict__ a_d2,
    const int* __restrict__ row_ptr, const int* __restrict__ esrc,
    const float* __restrict__ b2, const float* __restrict__ Wc1, const float* __restrict__ bc1,
    const float* __restrict__ Wc2, const float* __restrict__ bc2, float* __restrict__ out){
    int t = threadIdx.x;
    int wv = t >> 6, lane = t & 63;
    int n = blockIdx.x * 4 + wv;       // N divisible by 4
    int g = lane >> 3;                 // edge subgroup (0..7)
    int l = lane & 7;                  // owns dims 2l, 2l+1
    float adn = a_d2[n];
    const __half* hb2 = h2h + 2 * l;

    float den = 0.f, acc0 = 0.f, acc1 = 0.f;
    if (g == 0){
        float w = __expf(leaky(a_s2[n] + adn));
        den = w;
        float2 f = __half22float2(*(const __half2*)(hb2 + ((unsigned)n << 4)));
        acc0 = w * f.x; acc1 = w * f.y;
    }
    int start = row_ptr[n], end = row_ptr[n + 1];
    int len = end - start;
    int chunk = (len + 7) >> 3;
    int i = start + g * chunk;
    int e = i + chunk; if (e > end) e = end;
    for (; i + 3 < e; i += 4){
        int s0 = esrc[i], s1 = esrc[i + 1], s2 = esrc[i + 2], s3 = esrc[i + 3];
        float a0 = a_s2[s0], a1 = a_s2[s1], a2 = a_s2[s2], a3 = a_s2[s3];
        __half2 p0 = *(const __half2*)(hb2 + ((unsigned)s0 << 4));
        __half2 p1 = *(const __half2*)(hb2 + ((unsigned)s1 << 4));
        __half2 p2 = *(const __half2*)(hb2 + ((unsigned)s2 << 4));
        __half2 p3 = *(const __half2*)(hb2 + ((unsigned)s3 << 4));
        float w0 = __expf(leaky(a0 + adn));
        float w1 = __expf(leaky(a1 + adn));
        float w2 = __expf(leaky(a2 + adn));
        float w3 = __expf(leaky(a3 + adn));
        den += (w0 + w1) + (w2 + w3);
        float2 f0 = __half22float2(p0), f1 = __half22float2(p1);
        float2 f2 = __half22float2(p2), f3 = __half22float2(p3);
        acc0 += w0 * f0.x + w1 * f1.x + w2 * f2.x + w3 * f3.x;
        acc1 += w0 * f0.y + w1 * f1.y + w2 * f2.y + w3 * f3.y;
    }
    for (; i < e; i++){
        int s0 = esrc[i];
        float w0 = __expf(leaky(a_s2[s0] + adn));
        float2 f0 = __half22float2(*(const __half2*)(hb2 + ((unsigned)s0 << 4)));
        den += w0;
        acc0 += w0 * f0.x; acc1 += w0 * f0.y;
    }
    #pragma unroll
    for (int off = 8; off <= 32; off <<= 1){
        den  += __shfl_xor(den, off);
        acc0 += __shfl_xor(acc0, off);
        acc1 += __shfl_xor(acc1, off);
    }
    float inv = 1.f / (den + 1e-16f);
    float e0v = elu1(acc0 * inv + b2[2 * l]);
    float e1v = elu1(acc1 * inv + b2[2 * l + 1]);
    if (g == 0){
        float2 ov; ov.x = e0v; ov.y = e1v;
        *(float2*)(out + (size_t)n * 16 + 2 * l) = ov;
    }
    // classifier: each 8-lane cluster computes the full hidden layer redundantly
    float hid = bc1[l];
    #pragma unroll
    for (int j = 0; j < 8; j++){
        float a = __shfl(e0v, j, 8);
        float b = __shfl(e1v, j, 8);
        hid += a * Wc1[(2 * j) * 8 + l] + b * Wc1[(2 * j + 1) * 8 + l];
    }
    float contrib = fmaxf(hid, 0.f) * Wc2[l];
    contrib += __shfl_xor(contrib, 1);
    contrib += __shfl_xor(contrib, 2);
    contrib += __shfl_xor(contrib, 4);
    if (lane == 0) out[(size_t)N_NODES * 16 + n] = 1.f / (1.f + __expf(-(contrib + bc2[0])));
}

extern "C" void kernel_launch(void* const* d_in, const int* in_sizes, int n_in,
                              void* d_out, int out_size, void* d_ws, size_t ws_size,
                              hipStream_t stream){
    const float* x    = (const float*)d_in[0];
    const int*   ei   = (const int*)d_in[1];
    const float* W1   = (const float*)d_in[2];
    const float* as1w = (const float*)d_in[3];
    const float* ad1w = (const float*)d_in[4];
    const float* b1   = (const float*)d_in[5];
    const float* W2   = (const float*)d_in[6];
    const float* as2w = (const float*)d_in[7];
    const float* ad2w = (const float*)d_in[8];
    const float* b2   = (const float*)d_in[9];
    const float* Wc1  = (const float*)d_in[10];
    const float* bc1  = (const float*)d_in[11];
    const float* Wc2  = (const float*)d_in[12];
    const float* bc2  = (const float*)d_in[13];
    float* out = (float*)d_out;
    const int* src = ei;
    const int* dst = ei + N_EDGES;

    float* ws   = (float*)d_ws;
    float* a_s1 = ws;                                   // N*4
    float* a_d1 = a_s1 + (size_t)N_NODES * 4;           // N*4
    float* a_s2 = a_d1 + (size_t)N_NODES * 4;           // N
    float* a_d2 = a_s2 + N_NODES;                       // N
    __half* h1h  = (__half*)(a_d2 + N_NODES);           // N*128 f16
    __half* hL1h = h1h + (size_t)N_NODES * F1;          // N*128 f16
    __half* h2h  = hL1h + (size_t)N_NODES * F1;         // N*16 f16
    int* bucketCnt = (int*)(h2h + (size_t)N_NODES * 16);// NB
    int* row_ptr  = bucketCnt + NB;                     // N+1
    int* esrc     = row_ptr + N_NODES + 1;              // E
    unsigned int* ebuf = (unsigned int*)(esrc + N_EDGES); // NB*BCAP

    hipMemsetAsync(bucketCnt, 0, NB * sizeof(int), stream);
    k_build_dense1<<<NBLK_BIN + N_NODES / 8, 256, 0, stream>>>(
        src, dst, bucketCnt, ebuf, x, W1, as1w, ad1w, h1h, a_s1, a_d1);
    k_local_csr<<<NB, 256, 0, stream>>>(bucketCnt, ebuf, row_ptr, esrc);
    k_agg1<<<N_NODES / 4, 256, 0, stream>>>(h1h, a_s1, a_d1, row_ptr, esrc, b1, hL1h);
    k_dense2<<<N_NODES / 16, 256, 0, stream>>>(hL1h, W2, as2w, ad2w, h2h, a_s2, a_d2);
    k_agg2<<<N_NODES / 4, 256, 0, stream>>>(h2h, a_s2, a_d2, row_ptr, esrc, b2, Wc1, bc1, Wc2, bc2, out);
}